// Round 12
// baseline (652.688 us; speedup 1.0000x reference)
//
#include <hip/hip_runtime.h>

// ParallelExpert: grouped SwiGLU MLP, E=8 experts.
//   h = x @ w1 ; h_act = silu(gate)*val ; out = h_act @ w2
// Round 12: (a) gemm1 switched to mfma_f32_32x32x16_f16 (20% higher
//   FLOP/cyc on the matrix pipe, same LDS traffic & acc regs); epilogue
//   uses the m74/m101 32x32 C/D map row=(r&3)+8*(r>>2)+4*(lane>>5).
//   (b) transposes -> 64x64 tiles (float4 loads, b128 f16 stores).
// gemm2 8-phase unchanged (isolated variable).
// ws layout: [0,128M) hact f16; [128M,256M) w1t/w2t; [256M,288M) xh.

#define E_    8
#define T_    2048
#define DIN   1024
#define DHID  4096
#define DOUT  1024
#define INTER 8192

typedef _Float16 f16;
typedef _Float16 f16x8 __attribute__((ext_vector_type(8)));
typedef float    f32x4 __attribute__((ext_vector_type(4)));
typedef float    f32x16 __attribute__((ext_vector_type(16)));

typedef const __attribute__((address_space(1))) void gvoid_t;
typedef __attribute__((address_space(3))) void lvoid_t;

__device__ __forceinline__ void gload_lds16(const void* g, void* l) {
  __builtin_amdgcn_global_load_lds((gvoid_t*)g, (lvoid_t*)l, 16, 0, 0);
}

// ---- x f32 -> f16 bulk convert -------------------------------------------
__global__ __launch_bounds__(256) void conv_f32_f16(
    const float* __restrict__ src, f16* __restrict__ dst, int n8) {
  int i = blockIdx.x * 256 + threadIdx.x;
  int stride = gridDim.x * 256;
  for (; i < n8; i += stride) {
    const float4* s = (const float4*)(src + (size_t)i * 8);
    float4 a0 = s[0], a1 = s[1];
    f16x8 v;
    v[0] = (f16)a0.x; v[1] = (f16)a0.y; v[2] = (f16)a0.z; v[3] = (f16)a0.w;
    v[4] = (f16)a1.x; v[5] = (f16)a1.y; v[6] = (f16)a1.z; v[7] = (f16)a1.w;
    *(f16x8*)(dst + (size_t)i * 8) = v;
  }
}

// ---- transpose + convert, 64x64 tiles: f32 [E][R][C] -> f16 [E][C][R] -----
__global__ __launch_bounds__(256) void xpose64_f32_f16(
    const float* __restrict__ src, f16* __restrict__ dst,
    int R, int C, int tC) {
  __shared__ f16 tile[64][72];   // +8 f16 pad -> 2-way bank alias only
  int bid = blockIdx.x;
  int perE = (R >> 6) * tC;
  int e = bid / perE;
  int rem = bid - e * perE;
  int rt = rem / tC;
  int ct = rem - rt * tC;
  int r0 = rt << 6, c0 = ct << 6;
  int t = threadIdx.x;
  int lr  = t >> 2;          // 0..63
  int lc4 = (t & 3) * 16;    // 0,16,32,48
  const float* s = src + (size_t)e * R * C + (size_t)(r0 + lr) * C + c0 + lc4;
#pragma unroll
  for (int i = 0; i < 4; ++i) {
    float4 v = *(const float4*)(s + i * 4);
    tile[lr][lc4 + i * 4 + 0] = (f16)v.x;
    tile[lr][lc4 + i * 4 + 1] = (f16)v.y;
    tile[lr][lc4 + i * 4 + 2] = (f16)v.z;
    tile[lr][lc4 + i * 4 + 3] = (f16)v.w;
  }
  __syncthreads();
  // store: thread t writes output row (c0+lr), cols r0+lc4 .. +15 (32 B)
  f16* d = dst + (size_t)e * C * R + (size_t)(c0 + lr) * R + r0 + lc4;
  f16x8 o0, o1;
#pragma unroll
  for (int j = 0; j < 8; ++j) o0[j] = tile[lc4 + j][lr];
#pragma unroll
  for (int j = 0; j < 8; ++j) o1[j] = tile[lc4 + 8 + j][lr];
  *(f16x8*)(d)     = o0;
  *(f16x8*)(d + 8) = o1;
}

// ---- GEMM1 + SwiGLU (2-phase, 32x32x16 MFMA) ------------------------------
// xh:[E][T][DIN] f16, w1t:[E][INTER][DIN] f16, hact:[E][T][DHID] f16
// 512 threads = 8 waves (2M x 4N); block tile 128x128-dual; per-wave 64x32.
__global__ __launch_bounds__(512, 2) void gemm1_swiglu_xh(
    const f16* __restrict__ xh,
    const f16* __restrict__ w1t,
    f16* __restrict__ hact) {
  __shared__ f16 As[128][32];
  __shared__ f16 Bg[128][32];
  __shared__ f16 Bv[128][32];

  int bid = blockIdx.x;
  int e   = bid >> 9;
  int rem = bid & 511;
  int mt  = rem >> 5;
  int nt  = rem & 31;
  int m0 = mt * 128, n0 = nt * 128;

  const f16* xe = xh  + ((size_t)e * T_ + m0) * DIN;
  const f16* wg = w1t + ((size_t)e * INTER + n0) * DIN;
  const f16* wv = w1t + ((size_t)e * INTER + DHID + n0) * DIN;

  int tid  = threadIdx.x;
  int lane = tid & 63;
  int wid  = tid >> 6;           // 0..7

  int srow = wid * 16 + (lane >> 2);
  int scol = (lane & 3) * 8;
  f16* lA = &As[wid * 16][0];
  f16* lG = &Bg[wid * 16][0];
  f16* lV = &Bv[wid * 16][0];

  int wm  = wid >> 2;            // 0..1 -> rows wm*64..+63
  int wn  = wid & 3;             // 0..3 -> cols wn*32..+31
  int l31 = lane & 31;
  int lk2 = (lane >> 5) * 8;     // k-offset within a K=16 half

  f32x16 accG[2], accV[2];       // [mf] 32x32 tiles; 64 regs total
#pragma unroll
  for (int m = 0; m < 2; ++m) {
#pragma unroll
    for (int j = 0; j < 16; ++j) { accG[m][j] = 0.f; accV[m][j] = 0.f; }
  }

  for (int k = 0; k < DIN; k += 32) {
    __syncthreads();
    gload_lds16(xe + (size_t)srow * DIN + k + scol, lA);
    gload_lds16(wg + (size_t)srow * DIN + k + scol, lG);
    gload_lds16(wv + (size_t)srow * DIN + k + scol, lV);
    __syncthreads();

    f16x8 af[2][2], bg2[2], bv2[2];   // [mf][kh] / [kh]
#pragma unroll
    for (int mf = 0; mf < 2; ++mf)
#pragma unroll
      for (int kh = 0; kh < 2; ++kh)
        af[mf][kh] = *(const f16x8*)&As[wm * 64 + mf * 32 + l31][kh * 16 + lk2];
#pragma unroll
    for (int kh = 0; kh < 2; ++kh) {
      bg2[kh] = *(const f16x8*)&Bg[wn * 32 + l31][kh * 16 + lk2];
      bv2[kh] = *(const f16x8*)&Bv[wn * 32 + l31][kh * 16 + lk2];
    }
#pragma unroll
    for (int mf = 0; mf < 2; ++mf)
#pragma unroll
      for (int kh = 0; kh < 2; ++kh) {
        accG[mf] = __builtin_amdgcn_mfma_f32_32x32x16_f16(af[mf][kh], bg2[kh], accG[mf], 0, 0, 0);
        accV[mf] = __builtin_amdgcn_mfma_f32_32x32x16_f16(af[mf][kh], bv2[kh], accV[mf], 0, 0, 0);
      }
  }

  // epilogue: SwiGLU, store f16
  // 32x32 C/D: col = lane&31, row = (r&3) + 8*(r>>2) + 4*(lane>>5)  [m74/m101]
  f16* he = hact + (size_t)e * T_ * DHID;
  int lhi = lane >> 5;
  int col = n0 + wn * 32 + l31;
#pragma unroll
  for (int mf = 0; mf < 2; ++mf) {
    int rb = m0 + wm * 64 + mf * 32 + 4 * lhi;
#pragma unroll
    for (int r = 0; r < 16; ++r) {
      int row = rb + (r & 3) + 8 * (r >> 2);
      float g = accG[mf][r];
      float v = accV[mf][r];
      float s = g / (1.0f + __expf(-g));
      he[(size_t)row * DHID + col] = (f16)(s * v);
    }
  }
}

// ---- GEMM1 fallback (reg-staged fp32 A, 16x16 MFMA — proven) --------------
__global__ __launch_bounds__(512, 2) void gemm1_swiglu_rs(
    const float* __restrict__ x,
    const f16* __restrict__ w1t,
    f16* __restrict__ hact) {
  __shared__ f16 As[128][36];
  __shared__ f16 Bg[128][32];
  __shared__ f16 Bv[128][32];

  int bid = blockIdx.x;
  int e   = bid >> 9;
  int rem = bid & 511;
  int mt  = rem >> 5;
  int nt  = rem & 31;
  int m0 = mt * 128, n0 = nt * 128;

  const float* xe = x   + ((size_t)e * T_ + m0) * DIN;
  const f16*   wg = w1t + ((size_t)e * INTER + n0) * DIN;
  const f16*   wv = w1t + ((size_t)e * INTER + DHID + n0) * DIN;

  int tid  = threadIdx.x;
  int lane = tid & 63;
  int wid  = tid >> 6;

  int arow = tid >> 2;
  int acol = (tid & 3) * 8;
  int brow = wid * 16 + (lane >> 2);
  int bcol = (lane & 3) * 8;
  f16* lG = &Bg[wid * 16][0];
  f16* lV = &Bv[wid * 16][0];

  int wm = wid >> 2;
  int wn = wid & 3;
  int lr = lane & 15;
  int lk = (lane >> 4) * 8;

  f32x4 accG[4][2], accV[4][2];
#pragma unroll
  for (int m = 0; m < 4; ++m)
#pragma unroll
    for (int n = 0; n < 2; ++n) {
      accG[m][n] = f32x4{0.f, 0.f, 0.f, 0.f};
      accV[m][n] = f32x4{0.f, 0.f, 0.f, 0.f};
    }

  for (int k = 0; k < DIN; k += 32) {
    __syncthreads();
    gload_lds16(wg + (size_t)brow * DIN + k + bcol, lG);
    gload_lds16(wv + (size_t)brow * DIN + k + bcol, lV);
    {
      const float* sa = xe + (size_t)arow * DIN + k + acol;
      float4 a0 = ((const float4*)sa)[0];
      float4 a1 = ((const float4*)sa)[1];
      f16x8 v;
      v[0] = (f16)a0.x; v[1] = (f16)a0.y; v[2] = (f16)a0.z; v[3] = (f16)a0.w;
      v[4] = (f16)a1.x; v[5] = (f16)a1.y; v[6] = (f16)a1.z; v[7] = (f16)a1.w;
      *(f16x8*)&As[arow][acol] = v;
    }
    __syncthreads();

    f16x8 af[4], bg[2], bv[2];
#pragma unroll
    for (int m = 0; m < 4; ++m)
      af[m] = *(const f16x8*)&As[wm * 64 + m * 16 + lr][lk];
#pragma unroll
    for (int n = 0; n < 2; ++n) {
      bg[n] = *(const f16x8*)&Bg[wn * 32 + n * 16 + lr][lk];
      bv[n] = *(const f16x8*)&Bv[wn * 32 + n * 16 + lr][lk];
    }
#pragma unroll
    for (int m = 0; m < 4; ++m)
#pragma unroll
      for (int n = 0; n < 2; ++n) {
        accG[m][n] = __builtin_amdgcn_mfma_f32_16x16x32_f16(af[m], bg[n], accG[m][n], 0, 0, 0);
        accV[m][n] = __builtin_amdgcn_mfma_f32_16x16x32_f16(af[m], bv[n], accV[m][n], 0, 0, 0);
      }
  }

  f16* he = hact + (size_t)e * T_ * DHID;
  int rbase = m0 + wm * 64 + (lane >> 4) * 4;
  int cbase = n0 + wn * 32 + lr;
#pragma unroll
  for (int m = 0; m < 4; ++m)
#pragma unroll
    for (int n = 0; n < 2; ++n)
#pragma unroll
      for (int j = 0; j < 4; ++j) {
        int row = rbase + m * 16 + j;
        int col = cbase + n * 16;
        float g = accG[m][n][j];
        float v = accV[m][n][j];
        float s = g / (1.0f + __expf(-g));
        he[(size_t)row * DHID + col] = (f16)(s * v);
      }
}

// ---- GEMM2, 8-phase 256x256 (K=4096 = 64 K-tiles) — r11-proven ------------
__global__ __launch_bounds__(512, 2) void gemm2_8ph(
    const f16* __restrict__ hact,
    const f16* __restrict__ w2t,
    float* __restrict__ out) {
  __shared__ __align__(1024) f16 As[2][256][64];  // 64 KiB
  __shared__ __align__(1024) f16 Bs[2][256][64];  // 64 KiB

  int bid = blockIdx.x;
  int e   = bid >> 5;
  int rem = bid & 31;
  int mt  = rem >> 2;
  int nt  = rem & 3;
  int m0 = mt * 256, n0 = nt * 256;

  const f16* ha = hact + ((size_t)e * T_ + m0) * DHID;
  const f16* wb = w2t  + ((size_t)e * DOUT + n0) * DHID;

  int tid  = threadIdx.x;
  int lane = tid & 63;
  int wid  = tid >> 6;
  int wm   = wid >> 2;
  int wn   = wid & 3;
  int lr   = lane & 15;
  int l16  = lane >> 4;

  int srow = lane >> 3;
  int scol = ((lane & 7) ^ srow) * 8;

  auto stA = [&](int buf, int kt, int i) {
    int ci = wid + 8 * i;
    gload_lds16(ha + (size_t)(ci * 8 + srow) * DHID + kt * 64 + scol,
                (char*)&As[buf][0][0] + ci * 1024);
  };
  auto stB = [&](int buf, int kt, int i) {
    int ci = wid + 8 * i;
    gload_lds16(wb + (size_t)(ci * 8 + srow) * DHID + kt * 64 + scol,
                (char*)&Bs[buf][0][0] + ci * 1024);
  };

  f32x4 acc[8][4];
#pragma unroll
  for (int m = 0; m < 8; ++m)
#pragma unroll
    for (int n = 0; n < 4; ++n) acc[m][n] = f32x4{0.f, 0.f, 0.f, 0.f};

  f16x8 af[4][2], bf0[2][2], bf1[2][2];

#define READ_A2(b, MH)                                                       \
  _Pragma("unroll") for (int m = 0; m < 4; ++m)                              \
  _Pragma("unroll") for (int kk = 0; kk < 2; ++kk) {                         \
    int row_ = wm * 128 + (MH) * 64 + m * 16 + lr;                           \
    af[m][kk] = *(const f16x8*)((const char*)&As[b][0][0] + row_ * 128 +     \
                                (((kk * 4 + l16) ^ (lr & 7)) << 4));         \
  }
#define READ_B2(b, NH, DST)                                                  \
  _Pragma("unroll") for (int n = 0; n < 2; ++n)                              \
  _Pragma("unroll") for (int kk = 0; kk < 2; ++kk) {                         \
    int row_ = wn * 64 + (NH) * 32 + n * 16 + lr;                            \
    DST[n][kk] = *(const f16x8*)((const char*)&Bs[b][0][0] + row_ * 128 +    \
                                 (((kk * 4 + l16) ^ (lr & 7)) << 4));        \
  }
#define MFMA16Q(MH, NH, BB)                                                  \
  __builtin_amdgcn_s_setprio(1);                                            \
  _Pragma("unroll") for (int m = 0; m < 4; ++m)                              \
  _Pragma("unroll") for (int n = 0; n < 2; ++n)                              \
  _Pragma("unroll") for (int kk = 0; kk < 2; ++kk)                          \
    acc[(MH) * 4 + m][(NH) * 2 + n] = __builtin_amdgcn_mfma_f32_16x16x32_f16(\
        af[m][kk], BB[n][kk], acc[(MH) * 4 + m][(NH) * 2 + n], 0, 0, 0);     \
  __builtin_amdgcn_s_setprio(0);
#define BAR() __builtin_amdgcn_s_barrier()
#define LGKM0() asm volatile("s_waitcnt lgkmcnt(0)" ::: "memory")
#define VM6() asm volatile("s_waitcnt vmcnt(6)" ::: "memory")

  stA(0, 0, 0); stA(0, 0, 1); stA(0, 0, 2); stA(0, 0, 3);
  stB(0, 0, 0); stB(0, 0, 1); stB(0, 0, 2); stB(0, 0, 3);
  stB(1, 1, 0); stB(1, 1, 1); stB(1, 1, 2); stB(1, 1, 3);
  stA(1, 1, 0); stA(1, 1, 1);
  VM6();
  BAR();

  for (int it = 0; it < 32; ++it) {
    int tb = 2 * it + 1;
    int pa = (2 * it + 2) & 63;
    int pb = (2 * it + 3) & 63;

    READ_A2(0, 0); READ_B2(0, 0, bf0);
    stA(1, tb, 2); stA(1, tb, 3);
    BAR(); LGKM0();
    MFMA16Q(0, 0, bf0);
    BAR();

    READ_B2(0, 1, bf1);
    BAR(); LGKM0();
    MFMA16Q(0, 1, bf1);
    BAR();

    READ_A2(0, 1);
    stB(0, pa, 0); stB(0, pa, 1);
    BAR(); LGKM0();
    MFMA16Q(1, 0, bf0);
    BAR();

    stB(0, pa, 2); stB(0, pa, 3);
    stA(0, pa, 0); stA(0, pa, 1);
    BAR();
    MFMA16Q(1, 1, bf1);
    VM6();
    BAR();

    READ_A2(1, 0); READ_B2(1, 0, bf0);
    stA(0, pa, 2); stA(0, pa, 3);
    BAR(); LGKM0();
    MFMA16Q(0, 0, bf0);
    BAR();

    READ_B2(1, 1, bf1);
    BAR(); LGKM0();
    MFMA16Q(0, 1, bf1);
    BAR();

    READ_A2(1, 1);
    stB(1, pb, 0); stB(1, pb, 1);
    BAR(); LGKM0();
    MFMA16Q(1, 0, bf0);
    BAR();

    stB(1, pb, 2); stB(1, pb, 3);
    stA(1, pb, 0); stA(1, pb, 1);
    BAR();
    MFMA16Q(1, 1, bf1);
    VM6();
    BAR();
  }

#undef READ_A2
#undef READ_B2
#undef MFMA16Q
#undef BAR
#undef LGKM0
#undef VM6

  float* oe = out + (size_t)e * T_ * DOUT;
  int rbase = m0 + wm * 128 + l16 * 4;
  int cbase = n0 + wn * 64 + lr;
#pragma unroll
  for (int m = 0; m < 8; ++m)
#pragma unroll
    for (int n = 0; n < 4; ++n)
#pragma unroll
      for (int j = 0; j < 4; ++j) {
        int row = rbase + m * 16 + j;
        int col = cbase + n * 16;
        oe[(size_t)row * DOUT + col] = acc[m][n][j];
      }
}

extern "C" void kernel_launch(void* const* d_in, const int* in_sizes, int n_in,
                              void* d_out, int out_size, void* d_ws, size_t ws_size,
                              hipStream_t stream) {
  const float* x  = (const float*)d_in[0];
  const float* w1 = (const float*)d_in[1];
  const float* w2 = (const float*)d_in[2];
  float* out = (float*)d_out;

  const size_t HACT_B = (size_t)E_ * T_ * DHID * 2;    // 128 MB
  const size_t WT_B   = (size_t)E_ * INTER * DIN * 2;  // 128 MB
  const size_t XH_B   = (size_t)E_ * T_ * DIN * 2;     //  32 MB

  f16* hact = (f16*)d_ws;
  f16* wt   = (f16*)((char*)d_ws + HACT_B);

  // 1) w1 [E][DIN][INTER] -> w1t [E][INTER][DIN] (f16), 64x64 tiles
  xpose64_f32_f16<<<E_ * (DIN / 64) * (INTER / 64), 256, 0, stream>>>(
      w1, wt, DIN, INTER, INTER / 64);

  // 2) fused GEMM1 + SwiGLU (2-phase, 32x32x16)
  if (ws_size >= HACT_B + WT_B + XH_B) {
    f16* xxh = (f16*)((char*)d_ws + HACT_B + WT_B);
    conv_f32_f16<<<2048, 256, 0, stream>>>(x, xxh, E_ * T_ * DIN / 8);
    gemm1_swiglu_xh<<<E_ * 16 * 32, 512, 0, stream>>>(xxh, wt, hact);
  } else {
    gemm1_swiglu_rs<<<E_ * 16 * 32, 512, 0, stream>>>(x, wt, hact);
  }

  // 3) w2 [E][DHID][DOUT] -> w2t [E][DOUT][DHID] (f16), 64x64 tiles
  xpose64_f32_f16<<<E_ * (DHID / 64) * (DOUT / 64), 256, 0, stream>>>(
      w2, wt, DHID, DOUT, DOUT / 64);
  // 4) GEMM2 (8-phase, 256^2, 256 blocks = 1/CU)
  gemm2_8ph<<<E_ * 8 * 4, 512, 0, stream>>>(hact, wt, out);
}

// Round 13
// 600.590 us; speedup vs baseline: 1.0867x; 1.0867x over previous
//
#include <hip/hip_runtime.h>

// ParallelExpert: grouped SwiGLU MLP, E=8 experts.
//   h = x @ w1 ; h_act = silu(gate)*val ; out = h_act @ w2
// Round 13: gemm1 REVERTED to 16x16x32 2-phase (r11-proven 356us; the
//   32x32 shape tripled LDS bank conflicts: lanes 0..31 x 64B row stride
//   -> 16-way, and conflict fixes are timing-null at 2-phase). xpose64
//   and gemm2_8ph kept (r12 isolated xpose64 at ~-15us).
// ws layout: [0,128M) hact f16; [128M,256M) w1t/w2t; [256M,288M) xh.

#define E_    8
#define T_    2048
#define DIN   1024
#define DHID  4096
#define DOUT  1024
#define INTER 8192

typedef _Float16 f16;
typedef _Float16 f16x8 __attribute__((ext_vector_type(8)));
typedef float    f32x4 __attribute__((ext_vector_type(4)));

typedef const __attribute__((address_space(1))) void gvoid_t;
typedef __attribute__((address_space(3))) void lvoid_t;

__device__ __forceinline__ void gload_lds16(const void* g, void* l) {
  __builtin_amdgcn_global_load_lds((gvoid_t*)g, (lvoid_t*)l, 16, 0, 0);
}

// ---- x f32 -> f16 bulk convert -------------------------------------------
__global__ __launch_bounds__(256) void conv_f32_f16(
    const float* __restrict__ src, f16* __restrict__ dst, int n8) {
  int i = blockIdx.x * 256 + threadIdx.x;
  int stride = gridDim.x * 256;
  for (; i < n8; i += stride) {
    const float4* s = (const float4*)(src + (size_t)i * 8);
    float4 a0 = s[0], a1 = s[1];
    f16x8 v;
    v[0] = (f16)a0.x; v[1] = (f16)a0.y; v[2] = (f16)a0.z; v[3] = (f16)a0.w;
    v[4] = (f16)a1.x; v[5] = (f16)a1.y; v[6] = (f16)a1.z; v[7] = (f16)a1.w;
    *(f16x8*)(dst + (size_t)i * 8) = v;
  }
}

// ---- transpose + convert, 64x64 tiles: f32 [E][R][C] -> f16 [E][C][R] -----
__global__ __launch_bounds__(256) void xpose64_f32_f16(
    const float* __restrict__ src, f16* __restrict__ dst,
    int R, int C, int tC) {
  __shared__ f16 tile[64][72];   // +8 f16 pad -> 2-way bank alias only
  int bid = blockIdx.x;
  int perE = (R >> 6) * tC;
  int e = bid / perE;
  int rem = bid - e * perE;
  int rt = rem / tC;
  int ct = rem - rt * tC;
  int r0 = rt << 6, c0 = ct << 6;
  int t = threadIdx.x;
  int lr  = t >> 2;          // 0..63
  int lc4 = (t & 3) * 16;    // 0,16,32,48
  const float* s = src + (size_t)e * R * C + (size_t)(r0 + lr) * C + c0 + lc4;
#pragma unroll
  for (int i = 0; i < 4; ++i) {
    float4 v = *(const float4*)(s + i * 4);
    tile[lr][lc4 + i * 4 + 0] = (f16)v.x;
    tile[lr][lc4 + i * 4 + 1] = (f16)v.y;
    tile[lr][lc4 + i * 4 + 2] = (f16)v.z;
    tile[lr][lc4 + i * 4 + 3] = (f16)v.w;
  }
  __syncthreads();
  // store: thread t writes output row (c0+lr), cols r0+lc4 .. +15 (32 B)
  f16* d = dst + (size_t)e * C * R + (size_t)(c0 + lr) * R + r0 + lc4;
  f16x8 o0, o1;
#pragma unroll
  for (int j = 0; j < 8; ++j) o0[j] = tile[lc4 + j][lr];
#pragma unroll
  for (int j = 0; j < 8; ++j) o1[j] = tile[lc4 + 8 + j][lr];
  *(f16x8*)(d)     = o0;
  *(f16x8*)(d + 8) = o1;
}

// ---- GEMM1 + SwiGLU (2-phase, 16x16x32 MFMA — r11-proven) -----------------
// xh:[E][T][DIN] f16, w1t:[E][INTER][DIN] f16, hact:[E][T][DHID] f16
// 512 threads = 8 waves (2M x 4N); block tile 128x128; per-wave 64x32 dual.
__global__ __launch_bounds__(512, 2) void gemm1_swiglu_xh(
    const f16* __restrict__ xh,
    const f16* __restrict__ w1t,
    f16* __restrict__ hact) {
  __shared__ f16 As[128][32];
  __shared__ f16 Bg[128][32];
  __shared__ f16 Bv[128][32];

  int bid = blockIdx.x;
  int e   = bid >> 9;
  int rem = bid & 511;
  int mt  = rem >> 5;
  int nt  = rem & 31;
  int m0 = mt * 128, n0 = nt * 128;

  const f16* xe = xh  + ((size_t)e * T_ + m0) * DIN;
  const f16* wg = w1t + ((size_t)e * INTER + n0) * DIN;
  const f16* wv = w1t + ((size_t)e * INTER + DHID + n0) * DIN;

  int tid  = threadIdx.x;
  int lane = tid & 63;
  int wid  = tid >> 6;           // 0..7

  int srow = wid * 16 + (lane >> 2);
  int scol = (lane & 3) * 8;
  f16* lA = &As[wid * 16][0];
  f16* lG = &Bg[wid * 16][0];
  f16* lV = &Bv[wid * 16][0];

  int wm = wid >> 2;             // 0..1
  int wn = wid & 3;              // 0..3
  int lr = lane & 15;
  int lk = (lane >> 4) * 8;

  f32x4 accG[4][2], accV[4][2];
#pragma unroll
  for (int m = 0; m < 4; ++m)
#pragma unroll
    for (int n = 0; n < 2; ++n) {
      accG[m][n] = f32x4{0.f, 0.f, 0.f, 0.f};
      accV[m][n] = f32x4{0.f, 0.f, 0.f, 0.f};
    }

  for (int k = 0; k < DIN; k += 32) {
    __syncthreads();
    gload_lds16(xe + (size_t)srow * DIN + k + scol, lA);
    gload_lds16(wg + (size_t)srow * DIN + k + scol, lG);
    gload_lds16(wv + (size_t)srow * DIN + k + scol, lV);
    __syncthreads();

    f16x8 af[4], bg[2], bv[2];
#pragma unroll
    for (int m = 0; m < 4; ++m)
      af[m] = *(const f16x8*)&As[wm * 64 + m * 16 + lr][lk];
#pragma unroll
    for (int n = 0; n < 2; ++n) {
      bg[n] = *(const f16x8*)&Bg[wn * 32 + n * 16 + lr][lk];
      bv[n] = *(const f16x8*)&Bv[wn * 32 + n * 16 + lr][lk];
    }
#pragma unroll
    for (int m = 0; m < 4; ++m)
#pragma unroll
      for (int n = 0; n < 2; ++n) {
        accG[m][n] = __builtin_amdgcn_mfma_f32_16x16x32_f16(af[m], bg[n], accG[m][n], 0, 0, 0);
        accV[m][n] = __builtin_amdgcn_mfma_f32_16x16x32_f16(af[m], bv[n], accV[m][n], 0, 0, 0);
      }
  }

  f16* he = hact + (size_t)e * T_ * DHID;
  int rbase = m0 + wm * 64 + (lane >> 4) * 4;
  int cbase = n0 + wn * 32 + lr;
#pragma unroll
  for (int m = 0; m < 4; ++m)
#pragma unroll
    for (int n = 0; n < 2; ++n)
#pragma unroll
      for (int j = 0; j < 4; ++j) {
        int row = rbase + m * 16 + j;
        int col = cbase + n * 16;
        float g = accG[m][n][j];
        float v = accV[m][n][j];
        float s = g / (1.0f + __expf(-g));
        he[(size_t)row * DHID + col] = (f16)(s * v);
      }
}

// ---- GEMM1 fallback (reg-staged fp32 A), used if ws too small for xh ------
__global__ __launch_bounds__(512, 2) void gemm1_swiglu_rs(
    const float* __restrict__ x,
    const f16* __restrict__ w1t,
    f16* __restrict__ hact) {
  __shared__ f16 As[128][36];
  __shared__ f16 Bg[128][32];
  __shared__ f16 Bv[128][32];

  int bid = blockIdx.x;
  int e   = bid >> 9;
  int rem = bid & 511;
  int mt  = rem >> 5;
  int nt  = rem & 31;
  int m0 = mt * 128, n0 = nt * 128;

  const float* xe = x   + ((size_t)e * T_ + m0) * DIN;
  const f16*   wg = w1t + ((size_t)e * INTER + n0) * DIN;
  const f16*   wv = w1t + ((size_t)e * INTER + DHID + n0) * DIN;

  int tid  = threadIdx.x;
  int lane = tid & 63;
  int wid  = tid >> 6;

  int arow = tid >> 2;
  int acol = (tid & 3) * 8;
  int brow = wid * 16 + (lane >> 2);
  int bcol = (lane & 3) * 8;
  f16* lG = &Bg[wid * 16][0];
  f16* lV = &Bv[wid * 16][0];

  int wm = wid >> 2;
  int wn = wid & 3;
  int lr = lane & 15;
  int lk = (lane >> 4) * 8;

  f32x4 accG[4][2], accV[4][2];
#pragma unroll
  for (int m = 0; m < 4; ++m)
#pragma unroll
    for (int n = 0; n < 2; ++n) {
      accG[m][n] = f32x4{0.f, 0.f, 0.f, 0.f};
      accV[m][n] = f32x4{0.f, 0.f, 0.f, 0.f};
    }

  for (int k = 0; k < DIN; k += 32) {
    __syncthreads();
    gload_lds16(wg + (size_t)brow * DIN + k + bcol, lG);
    gload_lds16(wv + (size_t)brow * DIN + k + bcol, lV);
    {
      const float* sa = xe + (size_t)arow * DIN + k + acol;
      float4 a0 = ((const float4*)sa)[0];
      float4 a1 = ((const float4*)sa)[1];
      f16x8 v;
      v[0] = (f16)a0.x; v[1] = (f16)a0.y; v[2] = (f16)a0.z; v[3] = (f16)a0.w;
      v[4] = (f16)a1.x; v[5] = (f16)a1.y; v[6] = (f16)a1.z; v[7] = (f16)a1.w;
      *(f16x8*)&As[arow][acol] = v;
    }
    __syncthreads();

    f16x8 af[4], bg[2], bv[2];
#pragma unroll
    for (int m = 0; m < 4; ++m)
      af[m] = *(const f16x8*)&As[wm * 64 + m * 16 + lr][lk];
#pragma unroll
    for (int n = 0; n < 2; ++n) {
      bg[n] = *(const f16x8*)&Bg[wn * 32 + n * 16 + lr][lk];
      bv[n] = *(const f16x8*)&Bv[wn * 32 + n * 16 + lr][lk];
    }
#pragma unroll
    for (int m = 0; m < 4; ++m)
#pragma unroll
      for (int n = 0; n < 2; ++n) {
        accG[m][n] = __builtin_amdgcn_mfma_f32_16x16x32_f16(af[m], bg[n], accG[m][n], 0, 0, 0);
        accV[m][n] = __builtin_amdgcn_mfma_f32_16x16x32_f16(af[m], bv[n], accV[m][n], 0, 0, 0);
      }
  }

  f16* he = hact + (size_t)e * T_ * DHID;
  int rbase = m0 + wm * 64 + (lane >> 4) * 4;
  int cbase = n0 + wn * 32 + lr;
#pragma unroll
  for (int m = 0; m < 4; ++m)
#pragma unroll
    for (int n = 0; n < 2; ++n)
#pragma unroll
      for (int j = 0; j < 4; ++j) {
        int row = rbase + m * 16 + j;
        int col = cbase + n * 16;
        float g = accG[m][n][j];
        float v = accV[m][n][j];
        float s = g / (1.0f + __expf(-g));
        he[(size_t)row * DHID + col] = (f16)(s * v);
      }
}

// ---- GEMM2, 8-phase 256x256 (K=4096 = 64 K-tiles) — r11-proven ------------
__global__ __launch_bounds__(512, 2) void gemm2_8ph(
    const f16* __restrict__ hact,
    const f16* __restrict__ w2t,
    float* __restrict__ out) {
  __shared__ __align__(1024) f16 As[2][256][64];  // 64 KiB
  __shared__ __align__(1024) f16 Bs[2][256][64];  // 64 KiB

  int bid = blockIdx.x;
  int e   = bid >> 5;
  int rem = bid & 31;
  int mt  = rem >> 2;
  int nt  = rem & 3;
  int m0 = mt * 256, n0 = nt * 256;

  const f16* ha = hact + ((size_t)e * T_ + m0) * DHID;
  const f16* wb = w2t  + ((size_t)e * DOUT + n0) * DHID;

  int tid  = threadIdx.x;
  int lane = tid & 63;
  int wid  = tid >> 6;
  int wm   = wid >> 2;
  int wn   = wid & 3;
  int lr   = lane & 15;
  int l16  = lane >> 4;

  int srow = lane >> 3;
  int scol = ((lane & 7) ^ srow) * 8;

  auto stA = [&](int buf, int kt, int i) {
    int ci = wid + 8 * i;
    gload_lds16(ha + (size_t)(ci * 8 + srow) * DHID + kt * 64 + scol,
                (char*)&As[buf][0][0] + ci * 1024);
  };
  auto stB = [&](int buf, int kt, int i) {
    int ci = wid + 8 * i;
    gload_lds16(wb + (size_t)(ci * 8 + srow) * DHID + kt * 64 + scol,
                (char*)&Bs[buf][0][0] + ci * 1024);
  };

  f32x4 acc[8][4];
#pragma unroll
  for (int m = 0; m < 8; ++m)
#pragma unroll
    for (int n = 0; n < 4; ++n) acc[m][n] = f32x4{0.f, 0.f, 0.f, 0.f};

  f16x8 af[4][2], bf0[2][2], bf1[2][2];

#define READ_A2(b, MH)                                                       \
  _Pragma("unroll") for (int m = 0; m < 4; ++m)                              \
  _Pragma("unroll") for (int kk = 0; kk < 2; ++kk) {                         \
    int row_ = wm * 128 + (MH) * 64 + m * 16 + lr;                           \
    af[m][kk] = *(const f16x8*)((const char*)&As[b][0][0] + row_ * 128 +     \
                                (((kk * 4 + l16) ^ (lr & 7)) << 4));         \
  }
#define READ_B2(b, NH, DST)                                                  \
  _Pragma("unroll") for (int n = 0; n < 2; ++n)                              \
  _Pragma("unroll") for (int kk = 0; kk < 2; ++kk) {                         \
    int row_ = wn * 64 + (NH) * 32 + n * 16 + lr;                            \
    DST[n][kk] = *(const f16x8*)((const char*)&Bs[b][0][0] + row_ * 128 +    \
                                 (((kk * 4 + l16) ^ (lr & 7)) << 4));        \
  }
#define MFMA16Q(MH, NH, BB)                                                  \
  __builtin_amdgcn_s_setprio(1);                                            \
  _Pragma("unroll") for (int m = 0; m < 4; ++m)                              \
  _Pragma("unroll") for (int n = 0; n < 2; ++n)                              \
  _Pragma("unroll") for (int kk = 0; kk < 2; ++kk)                          \
    acc[(MH) * 4 + m][(NH) * 2 + n] = __builtin_amdgcn_mfma_f32_16x16x32_f16(\
        af[m][kk], BB[n][kk], acc[(MH) * 4 + m][(NH) * 2 + n], 0, 0, 0);     \
  __builtin_amdgcn_s_setprio(0);
#define BAR() __builtin_amdgcn_s_barrier()
#define LGKM0() asm volatile("s_waitcnt lgkmcnt(0)" ::: "memory")
#define VM6() asm volatile("s_waitcnt vmcnt(6)" ::: "memory")

  stA(0, 0, 0); stA(0, 0, 1); stA(0, 0, 2); stA(0, 0, 3);
  stB(0, 0, 0); stB(0, 0, 1); stB(0, 0, 2); stB(0, 0, 3);
  stB(1, 1, 0); stB(1, 1, 1); stB(1, 1, 2); stB(1, 1, 3);
  stA(1, 1, 0); stA(1, 1, 1);
  VM6();
  BAR();

  for (int it = 0; it < 32; ++it) {
    int tb = 2 * it + 1;
    int pa = (2 * it + 2) & 63;
    int pb = (2 * it + 3) & 63;

    READ_A2(0, 0); READ_B2(0, 0, bf0);
    stA(1, tb, 2); stA(1, tb, 3);
    BAR(); LGKM0();
    MFMA16Q(0, 0, bf0);
    BAR();

    READ_B2(0, 1, bf1);
    BAR(); LGKM0();
    MFMA16Q(0, 1, bf1);
    BAR();

    READ_A2(0, 1);
    stB(0, pa, 0); stB(0, pa, 1);
    BAR(); LGKM0();
    MFMA16Q(1, 0, bf0);
    BAR();

    stB(0, pa, 2); stB(0, pa, 3);
    stA(0, pa, 0); stA(0, pa, 1);
    BAR();
    MFMA16Q(1, 1, bf1);
    VM6();
    BAR();

    READ_A2(1, 0); READ_B2(1, 0, bf0);
    stA(0, pa, 2); stA(0, pa, 3);
    BAR(); LGKM0();
    MFMA16Q(0, 0, bf0);
    BAR();

    READ_B2(1, 1, bf1);
    BAR(); LGKM0();
    MFMA16Q(0, 1, bf1);
    BAR();

    READ_A2(1, 1);
    stB(1, pb, 0); stB(1, pb, 1);
    BAR(); LGKM0();
    MFMA16Q(1, 0, bf0);
    BAR();

    stB(1, pb, 2); stB(1, pb, 3);
    stA(1, pb, 0); stA(1, pb, 1);
    BAR();
    MFMA16Q(1, 1, bf1);
    VM6();
    BAR();
  }

#undef READ_A2
#undef READ_B2
#undef MFMA16Q
#undef BAR
#undef LGKM0
#undef VM6

  float* oe = out + (size_t)e * T_ * DOUT;
  int rbase = m0 + wm * 128 + l16 * 4;
  int cbase = n0 + wn * 64 + lr;
#pragma unroll
  for (int m = 0; m < 8; ++m)
#pragma unroll
    for (int n = 0; n < 4; ++n)
#pragma unroll
      for (int j = 0; j < 4; ++j) {
        int row = rbase + m * 16 + j;
        int col = cbase + n * 16;
        oe[(size_t)row * DOUT + col] = acc[m][n][j];
      }
}

extern "C" void kernel_launch(void* const* d_in, const int* in_sizes, int n_in,
                              void* d_out, int out_size, void* d_ws, size_t ws_size,
                              hipStream_t stream) {
  const float* x  = (const float*)d_in[0];
  const float* w1 = (const float*)d_in[1];
  const float* w2 = (const float*)d_in[2];
  float* out = (float*)d_out;

  const size_t HACT_B = (size_t)E_ * T_ * DHID * 2;    // 128 MB
  const size_t WT_B   = (size_t)E_ * INTER * DIN * 2;  // 128 MB
  const size_t XH_B   = (size_t)E_ * T_ * DIN * 2;     //  32 MB

  f16* hact = (f16*)d_ws;
  f16* wt   = (f16*)((char*)d_ws + HACT_B);

  // 1) w1 [E][DIN][INTER] -> w1t [E][INTER][DIN] (f16), 64x64 tiles
  xpose64_f32_f16<<<E_ * (DIN / 64) * (INTER / 64), 256, 0, stream>>>(
      w1, wt, DIN, INTER, INTER / 64);

  // 2) fused GEMM1 + SwiGLU (2-phase, 16x16x32)
  if (ws_size >= HACT_B + WT_B + XH_B) {
    f16* xxh = (f16*)((char*)d_ws + HACT_B + WT_B);
    conv_f32_f16<<<2048, 256, 0, stream>>>(x, xxh, E_ * T_ * DIN / 8);
    gemm1_swiglu_xh<<<E_ * 16 * 32, 512, 0, stream>>>(xxh, wt, hact);
  } else {
    gemm1_swiglu_rs<<<E_ * 16 * 32, 512, 0, stream>>>(x, wt, hact);
  }

  // 3) w2 [E][DHID][DOUT] -> w2t [E][DOUT][DHID] (f16), 64x64 tiles
  xpose64_f32_f16<<<E_ * (DHID / 64) * (DOUT / 64), 256, 0, stream>>>(
      w2, wt, DHID, DOUT, DOUT / 64);
  // 4) GEMM2 (8-phase, 256^2, 256 blocks = 1/CU)
  gemm2_8ph<<<E_ * 8 * 4, 512, 0, stream>>>(hact, wt, out);
}

// Round 14
// 564.509 us; speedup vs baseline: 1.1562x; 1.0639x over previous
//
#include <hip/hip_runtime.h>

// ParallelExpert: grouped SwiGLU MLP, E=8 experts.
//   h = x @ w1 ; h_act = silu(gate)*val ; out = h_act @ w2
// Round 14: gemm1 -> BK=64 2-phase (halves per-FLOP barrier+vmcnt-drain
//   cost; 48KB LDS keeps 3-block/CU cap above the measured ~1.9 binding).
//   128B LDS rows REQUIRE the gemm2_8ph swizzle (else 16-way conflicts,
//   r12): linear dest + pre-swizzled gload source + swizzled read quad.
// xpose64, conv, gemm2_8ph unchanged.
// ws layout: [0,128M) hact f16; [128M,256M) w1t/w2t; [256M,288M) xh.

#define E_    8
#define T_    2048
#define DIN   1024
#define DHID  4096
#define DOUT  1024
#define INTER 8192

typedef _Float16 f16;
typedef _Float16 f16x8 __attribute__((ext_vector_type(8)));
typedef float    f32x4 __attribute__((ext_vector_type(4)));

typedef const __attribute__((address_space(1))) void gvoid_t;
typedef __attribute__((address_space(3))) void lvoid_t;

__device__ __forceinline__ void gload_lds16(const void* g, void* l) {
  __builtin_amdgcn_global_load_lds((gvoid_t*)g, (lvoid_t*)l, 16, 0, 0);
}

// ---- x f32 -> f16 bulk convert -------------------------------------------
__global__ __launch_bounds__(256) void conv_f32_f16(
    const float* __restrict__ src, f16* __restrict__ dst, int n8) {
  int i = blockIdx.x * 256 + threadIdx.x;
  int stride = gridDim.x * 256;
  for (; i < n8; i += stride) {
    const float4* s = (const float4*)(src + (size_t)i * 8);
    float4 a0 = s[0], a1 = s[1];
    f16x8 v;
    v[0] = (f16)a0.x; v[1] = (f16)a0.y; v[2] = (f16)a0.z; v[3] = (f16)a0.w;
    v[4] = (f16)a1.x; v[5] = (f16)a1.y; v[6] = (f16)a1.z; v[7] = (f16)a1.w;
    *(f16x8*)(dst + (size_t)i * 8) = v;
  }
}

// ---- transpose + convert, 64x64 tiles: f32 [E][R][C] -> f16 [E][C][R] -----
__global__ __launch_bounds__(256) void xpose64_f32_f16(
    const float* __restrict__ src, f16* __restrict__ dst,
    int R, int C, int tC) {
  __shared__ f16 tile[64][72];   // +8 f16 pad -> 2-way bank alias only
  int bid = blockIdx.x;
  int perE = (R >> 6) * tC;
  int e = bid / perE;
  int rem = bid - e * perE;
  int rt = rem / tC;
  int ct = rem - rt * tC;
  int r0 = rt << 6, c0 = ct << 6;
  int t = threadIdx.x;
  int lr  = t >> 2;          // 0..63
  int lc4 = (t & 3) * 16;    // 0,16,32,48
  const float* s = src + (size_t)e * R * C + (size_t)(r0 + lr) * C + c0 + lc4;
#pragma unroll
  for (int i = 0; i < 4; ++i) {
    float4 v = *(const float4*)(s + i * 4);
    tile[lr][lc4 + i * 4 + 0] = (f16)v.x;
    tile[lr][lc4 + i * 4 + 1] = (f16)v.y;
    tile[lr][lc4 + i * 4 + 2] = (f16)v.z;
    tile[lr][lc4 + i * 4 + 3] = (f16)v.w;
  }
  __syncthreads();
  f16* d = dst + (size_t)e * C * R + (size_t)(c0 + lr) * R + r0 + lc4;
  f16x8 o0, o1;
#pragma unroll
  for (int j = 0; j < 8; ++j) o0[j] = tile[lc4 + j][lr];
#pragma unroll
  for (int j = 0; j < 8; ++j) o1[j] = tile[lc4 + 8 + j][lr];
  *(f16x8*)(d)     = o0;
  *(f16x8*)(d + 8) = o1;
}

// ---- GEMM1 + SwiGLU (2-phase, BK=64, swizzled 128B rows) ------------------
// xh:[E][T][DIN] f16, w1t:[E][INTER][DIN] f16, hact:[E][T][DHID] f16
// 512 threads = 8 waves (2M x 4N); block tile 128x128-dual; per-wave 64x32.
__global__ __launch_bounds__(512, 2) void gemm1_swiglu_xh(
    const f16* __restrict__ xh,
    const f16* __restrict__ w1t,
    f16* __restrict__ hact) {
  __shared__ __align__(1024) f16 As[128][64];   // 16 KiB each
  __shared__ __align__(1024) f16 Bg[128][64];
  __shared__ __align__(1024) f16 Bv[128][64];

  int bid = blockIdx.x;
  int e   = bid >> 9;
  int rem = bid & 511;
  int mt  = rem >> 5;
  int nt  = rem & 31;
  int m0 = mt * 128, n0 = nt * 128;

  const f16* xe = xh  + ((size_t)e * T_ + m0) * DIN;
  const f16* wg = w1t + ((size_t)e * INTER + n0) * DIN;
  const f16* wv = w1t + ((size_t)e * INTER + DHID + n0) * DIN;

  int tid  = threadIdx.x;
  int lane = tid & 63;
  int wid  = tid >> 6;           // 0..7

  // staging: 1KB chunk = 8 rows x 128B; linear LDS dest, pre-swizzled source
  int srow8 = lane >> 3;                   // row in chunk 0..7
  int scol  = ((lane & 7) ^ srow8) * 8;    // involution quad ^= row&7

  auto stA = [&](int kt, int i) {
    int ci = wid + 8 * i;  // chunk 0..15 (rows ci*8..+7)
    gload_lds16(xe + (size_t)(ci * 8 + srow8) * DIN + kt * 64 + scol,
                (char*)&As[0][0] + ci * 1024);
  };
  auto stG = [&](int kt, int i) {
    int ci = wid + 8 * i;
    gload_lds16(wg + (size_t)(ci * 8 + srow8) * DIN + kt * 64 + scol,
                (char*)&Bg[0][0] + ci * 1024);
  };
  auto stV = [&](int kt, int i) {
    int ci = wid + 8 * i;
    gload_lds16(wv + (size_t)(ci * 8 + srow8) * DIN + kt * 64 + scol,
                (char*)&Bv[0][0] + ci * 1024);
  };

  int wm  = wid >> 2;            // 0..1
  int wn  = wid & 3;             // 0..3
  int lr  = lane & 15;
  int l16 = lane >> 4;           // 0..3

  f32x4 accG[4][2], accV[4][2];
#pragma unroll
  for (int m = 0; m < 4; ++m)
#pragma unroll
    for (int n = 0; n < 2; ++n) {
      accG[m][n] = f32x4{0.f, 0.f, 0.f, 0.f};
      accV[m][n] = f32x4{0.f, 0.f, 0.f, 0.f};
    }

  for (int kt = 0; kt < DIN / 64; ++kt) {   // 16 K-steps
    __syncthreads();
    stA(kt, 0); stA(kt, 1);
    stG(kt, 0); stG(kt, 1);
    stV(kt, 0); stV(kt, 1);
    __syncthreads();   // compiler drains vmcnt -> tiles ready

    // swizzled fragment reads: row_*128B + quad ((kk*4+l16)^(row_&7))*16
    f16x8 af[4][2], bg[2][2], bv[2][2];
#pragma unroll
    for (int m = 0; m < 4; ++m)
#pragma unroll
      for (int kk = 0; kk < 2; ++kk) {
        int row_ = wm * 64 + m * 16 + lr;
        af[m][kk] = *(const f16x8*)((const char*)&As[0][0] + row_ * 128 +
                                    (((kk * 4 + l16) ^ (lr & 7)) << 4));
      }
#pragma unroll
    for (int n = 0; n < 2; ++n)
#pragma unroll
      for (int kk = 0; kk < 2; ++kk) {
        int row_ = wn * 32 + n * 16 + lr;
        bg[n][kk] = *(const f16x8*)((const char*)&Bg[0][0] + row_ * 128 +
                                    (((kk * 4 + l16) ^ (lr & 7)) << 4));
        bv[n][kk] = *(const f16x8*)((const char*)&Bv[0][0] + row_ * 128 +
                                    (((kk * 4 + l16) ^ (lr & 7)) << 4));
      }
#pragma unroll
    for (int m = 0; m < 4; ++m)
#pragma unroll
      for (int n = 0; n < 2; ++n)
#pragma unroll
        for (int kk = 0; kk < 2; ++kk) {
          accG[m][n] = __builtin_amdgcn_mfma_f32_16x16x32_f16(af[m][kk], bg[n][kk], accG[m][n], 0, 0, 0);
          accV[m][n] = __builtin_amdgcn_mfma_f32_16x16x32_f16(af[m][kk], bv[n][kk], accV[m][n], 0, 0, 0);
        }
  }

  // epilogue: SwiGLU, store f16 (16x16 C/D: col=lane&15, row=(lane>>4)*4+j)
  f16* he = hact + (size_t)e * T_ * DHID;
  int rbase = m0 + wm * 64 + l16 * 4;
  int cbase = n0 + wn * 32 + lr;
#pragma unroll
  for (int m = 0; m < 4; ++m)
#pragma unroll
    for (int n = 0; n < 2; ++n)
#pragma unroll
      for (int j = 0; j < 4; ++j) {
        int row = rbase + m * 16 + j;
        int col = cbase + n * 16;
        float g = accG[m][n][j];
        float v = accV[m][n][j];
        float s = g / (1.0f + __expf(-g));
        he[(size_t)row * DHID + col] = (f16)(s * v);
      }
}

// ---- GEMM1 fallback (reg-staged fp32 A), used if ws too small for xh ------
__global__ __launch_bounds__(512, 2) void gemm1_swiglu_rs(
    const float* __restrict__ x,
    const f16* __restrict__ w1t,
    f16* __restrict__ hact) {
  __shared__ f16 As[128][36];
  __shared__ f16 Bg[128][32];
  __shared__ f16 Bv[128][32];

  int bid = blockIdx.x;
  int e   = bid >> 9;
  int rem = bid & 511;
  int mt  = rem >> 5;
  int nt  = rem & 31;
  int m0 = mt * 128, n0 = nt * 128;

  const float* xe = x   + ((size_t)e * T_ + m0) * DIN;
  const f16*   wg = w1t + ((size_t)e * INTER + n0) * DIN;
  const f16*   wv = w1t + ((size_t)e * INTER + DHID + n0) * DIN;

  int tid  = threadIdx.x;
  int lane = tid & 63;
  int wid  = tid >> 6;

  int arow = tid >> 2;
  int acol = (tid & 3) * 8;
  int brow = wid * 16 + (lane >> 2);
  int bcol = (lane & 3) * 8;
  f16* lG = &Bg[wid * 16][0];
  f16* lV = &Bv[wid * 16][0];

  int wm = wid >> 2;
  int wn = wid & 3;
  int lr = lane & 15;
  int lk = (lane >> 4) * 8;

  f32x4 accG[4][2], accV[4][2];
#pragma unroll
  for (int m = 0; m < 4; ++m)
#pragma unroll
    for (int n = 0; n < 2; ++n) {
      accG[m][n] = f32x4{0.f, 0.f, 0.f, 0.f};
      accV[m][n] = f32x4{0.f, 0.f, 0.f, 0.f};
    }

  for (int k = 0; k < DIN; k += 32) {
    __syncthreads();
    gload_lds16(wg + (size_t)brow * DIN + k + bcol, lG);
    gload_lds16(wv + (size_t)brow * DIN + k + bcol, lV);
    {
      const float* sa = xe + (size_t)arow * DIN + k + acol;
      float4 a0 = ((const float4*)sa)[0];
      float4 a1 = ((const float4*)sa)[1];
      f16x8 v;
      v[0] = (f16)a0.x; v[1] = (f16)a0.y; v[2] = (f16)a0.z; v[3] = (f16)a0.w;
      v[4] = (f16)a1.x; v[5] = (f16)a1.y; v[6] = (f16)a1.z; v[7] = (f16)a1.w;
      *(f16x8*)&As[arow][acol] = v;
    }
    __syncthreads();

    f16x8 af[4], bg[2], bv[2];
#pragma unroll
    for (int m = 0; m < 4; ++m)
      af[m] = *(const f16x8*)&As[wm * 64 + m * 16 + lr][lk];
#pragma unroll
    for (int n = 0; n < 2; ++n) {
      bg[n] = *(const f16x8*)&Bg[wn * 32 + n * 16 + lr][lk];
      bv[n] = *(const f16x8*)&Bv[wn * 32 + n * 16 + lr][lk];
    }
#pragma unroll
    for (int m = 0; m < 4; ++m)
#pragma unroll
      for (int n = 0; n < 2; ++n) {
        accG[m][n] = __builtin_amdgcn_mfma_f32_16x16x32_f16(af[m], bg[n], accG[m][n], 0, 0, 0);
        accV[m][n] = __builtin_amdgcn_mfma_f32_16x16x32_f16(af[m], bv[n], accV[m][n], 0, 0, 0);
      }
  }

  f16* he = hact + (size_t)e * T_ * DHID;
  int rbase = m0 + wm * 64 + (lane >> 4) * 4;
  int cbase = n0 + wn * 32 + lr;
#pragma unroll
  for (int m = 0; m < 4; ++m)
#pragma unroll
    for (int n = 0; n < 2; ++n)
#pragma unroll
      for (int j = 0; j < 4; ++j) {
        int row = rbase + m * 16 + j;
        int col = cbase + n * 16;
        float g = accG[m][n][j];
        float v = accV[m][n][j];
        float s = g / (1.0f + __expf(-g));
        he[(size_t)row * DHID + col] = (f16)(s * v);
      }
}

// ---- GEMM2, 8-phase 256x256 (K=4096 = 64 K-tiles) — r11-proven ------------
__global__ __launch_bounds__(512, 2) void gemm2_8ph(
    const f16* __restrict__ hact,
    const f16* __restrict__ w2t,
    float* __restrict__ out) {
  __shared__ __align__(1024) f16 As[2][256][64];  // 64 KiB
  __shared__ __align__(1024) f16 Bs[2][256][64];  // 64 KiB

  int bid = blockIdx.x;
  int e   = bid >> 5;
  int rem = bid & 31;
  int mt  = rem >> 2;
  int nt  = rem & 3;
  int m0 = mt * 256, n0 = nt * 256;

  const f16* ha = hact + ((size_t)e * T_ + m0) * DHID;
  const f16* wb = w2t  + ((size_t)e * DOUT + n0) * DHID;

  int tid  = threadIdx.x;
  int lane = tid & 63;
  int wid  = tid >> 6;
  int wm   = wid >> 2;
  int wn   = wid & 3;
  int lr   = lane & 15;
  int l16  = lane >> 4;

  int srow = lane >> 3;
  int scol = ((lane & 7) ^ srow) * 8;

  auto stA = [&](int buf, int kt, int i) {
    int ci = wid + 8 * i;
    gload_lds16(ha + (size_t)(ci * 8 + srow) * DHID + kt * 64 + scol,
                (char*)&As[buf][0][0] + ci * 1024);
  };
  auto stB = [&](int buf, int kt, int i) {
    int ci = wid + 8 * i;
    gload_lds16(wb + (size_t)(ci * 8 + srow) * DHID + kt * 64 + scol,
                (char*)&Bs[buf][0][0] + ci * 1024);
  };

  f32x4 acc[8][4];
#pragma unroll
  for (int m = 0; m < 8; ++m)
#pragma unroll
    for (int n = 0; n < 4; ++n) acc[m][n] = f32x4{0.f, 0.f, 0.f, 0.f};

  f16x8 af[4][2], bf0[2][2], bf1[2][2];

#define READ_A2(b, MH)                                                       \
  _Pragma("unroll") for (int m = 0; m < 4; ++m)                              \
  _Pragma("unroll") for (int kk = 0; kk < 2; ++kk) {                         \
    int row_ = wm * 128 + (MH) * 64 + m * 16 + lr;                           \
    af[m][kk] = *(const f16x8*)((const char*)&As[b][0][0] + row_ * 128 +     \
                                (((kk * 4 + l16) ^ (lr & 7)) << 4));         \
  }
#define READ_B2(b, NH, DST)                                                  \
  _Pragma("unroll") for (int n = 0; n < 2; ++n)                              \
  _Pragma("unroll") for (int kk = 0; kk < 2; ++kk) {                         \
    int row_ = wn * 64 + (NH) * 32 + n * 16 + lr;                            \
    DST[n][kk] = *(const f16x8*)((const char*)&Bs[b][0][0] + row_ * 128 +    \
                                 (((kk * 4 + l16) ^ (lr & 7)) << 4));        \
  }
#define MFMA16Q(MH, NH, BB)                                                  \
  __builtin_amdgcn_s_setprio(1);                                            \
  _Pragma("unroll") for (int m = 0; m < 4; ++m)                              \
  _Pragma("unroll") for (int n = 0; n < 2; ++n)                              \
  _Pragma("unroll") for (int kk = 0; kk < 2; ++kk)                          \
    acc[(MH) * 4 + m][(NH) * 2 + n] = __builtin_amdgcn_mfma_f32_16x16x32_f16(\
        af[m][kk], BB[n][kk], acc[(MH) * 4 + m][(NH) * 2 + n], 0, 0, 0);     \
  __builtin_amdgcn_s_setprio(0);
#define BAR() __builtin_amdgcn_s_barrier()
#define LGKM0() asm volatile("s_waitcnt lgkmcnt(0)" ::: "memory")
#define VM6() asm volatile("s_waitcnt vmcnt(6)" ::: "memory")

  stA(0, 0, 0); stA(0, 0, 1); stA(0, 0, 2); stA(0, 0, 3);
  stB(0, 0, 0); stB(0, 0, 1); stB(0, 0, 2); stB(0, 0, 3);
  stB(1, 1, 0); stB(1, 1, 1); stB(1, 1, 2); stB(1, 1, 3);
  stA(1, 1, 0); stA(1, 1, 1);
  VM6();
  BAR();

  for (int it = 0; it < 32; ++it) {
    int tb = 2 * it + 1;
    int pa = (2 * it + 2) & 63;
    int pb = (2 * it + 3) & 63;

    READ_A2(0, 0); READ_B2(0, 0, bf0);
    stA(1, tb, 2); stA(1, tb, 3);
    BAR(); LGKM0();
    MFMA16Q(0, 0, bf0);
    BAR();

    READ_B2(0, 1, bf1);
    BAR(); LGKM0();
    MFMA16Q(0, 1, bf1);
    BAR();

    READ_A2(0, 1);
    stB(0, pa, 0); stB(0, pa, 1);
    BAR(); LGKM0();
    MFMA16Q(1, 0, bf0);
    BAR();

    stB(0, pa, 2); stB(0, pa, 3);
    stA(0, pa, 0); stA(0, pa, 1);
    BAR();
    MFMA16Q(1, 1, bf1);
    VM6();
    BAR();

    READ_A2(1, 0); READ_B2(1, 0, bf0);
    stA(0, pa, 2); stA(0, pa, 3);
    BAR(); LGKM0();
    MFMA16Q(0, 0, bf0);
    BAR();

    READ_B2(1, 1, bf1);
    BAR(); LGKM0();
    MFMA16Q(0, 1, bf1);
    BAR();

    READ_A2(1, 1);
    stB(1, pb, 0); stB(1, pb, 1);
    BAR(); LGKM0();
    MFMA16Q(1, 0, bf0);
    BAR();

    stB(1, pb, 2); stB(1, pb, 3);
    stA(1, pb, 0); stA(1, pb, 1);
    BAR();
    MFMA16Q(1, 1, bf1);
    VM6();
    BAR();
  }

#undef READ_A2
#undef READ_B2
#undef MFMA16Q
#undef BAR
#undef LGKM0
#undef VM6

  float* oe = out + (size_t)e * T_ * DOUT;
  int rbase = m0 + wm * 128 + l16 * 4;
  int cbase = n0 + wn * 64 + lr;
#pragma unroll
  for (int m = 0; m < 8; ++m)
#pragma unroll
    for (int n = 0; n < 4; ++n)
#pragma unroll
      for (int j = 0; j < 4; ++j) {
        int row = rbase + m * 16 + j;
        int col = cbase + n * 16;
        oe[(size_t)row * DOUT + col] = acc[m][n][j];
      }
}

extern "C" void kernel_launch(void* const* d_in, const int* in_sizes, int n_in,
                              void* d_out, int out_size, void* d_ws, size_t ws_size,
                              hipStream_t stream) {
  const float* x  = (const float*)d_in[0];
  const float* w1 = (const float*)d_in[1];
  const float* w2 = (const float*)d_in[2];
  float* out = (float*)d_out;

  const size_t HACT_B = (size_t)E_ * T_ * DHID * 2;    // 128 MB
  const size_t WT_B   = (size_t)E_ * INTER * DIN * 2;  // 128 MB
  const size_t XH_B   = (size_t)E_ * T_ * DIN * 2;     //  32 MB

  f16* hact = (f16*)d_ws;
  f16* wt   = (f16*)((char*)d_ws + HACT_B);

  // 1) w1 [E][DIN][INTER] -> w1t [E][INTER][DIN] (f16), 64x64 tiles
  xpose64_f32_f16<<<E_ * (DIN / 64) * (INTER / 64), 256, 0, stream>>>(
      w1, wt, DIN, INTER, INTER / 64);

  // 2) fused GEMM1 + SwiGLU (2-phase, BK=64, swizzled)
  if (ws_size >= HACT_B + WT_B + XH_B) {
    f16* xxh = (f16*)((char*)d_ws + HACT_B + WT_B);
    conv_f32_f16<<<2048, 256, 0, stream>>>(x, xxh, E_ * T_ * DIN / 8);
    gemm1_swiglu_xh<<<E_ * 16 * 32, 512, 0, stream>>>(xxh, wt, hact);
  } else {
    gemm1_swiglu_rs<<<E_ * 16 * 32, 512, 0, stream>>>(x, wt, hact);
  }

  // 3) w2 [E][DHID][DOUT] -> w2t [E][DOUT][DHID] (f16), 64x64 tiles
  xpose64_f32_f16<<<E_ * (DHID / 64) * (DOUT / 64), 256, 0, stream>>>(
      w2, wt, DHID, DOUT, DOUT / 64);
  // 4) GEMM2 (8-phase, 256^2, 256 blocks = 1/CU)
  gemm2_8ph<<<E_ * 8 * 4, 512, 0, stream>>>(hact, wt, out);
}